// Round 8
// baseline (1414.846 us; speedup 1.0000x reference)
//
#include <hip/hip_runtime.h>
#include <stdint.h>

typedef __attribute__((ext_vector_type(4))) float  f32x4;
typedef __attribute__((ext_vector_type(8))) short  short8;
typedef __attribute__((ext_vector_type(4))) short  short4v;
typedef __attribute__((ext_vector_type(2))) unsigned int uint2v;

#define DEV __device__ __forceinline__

DEV float b2f(unsigned short u) { return __uint_as_float(((unsigned)u) << 16); }
DEV unsigned short f2b(float f) {
  unsigned u = __float_as_uint(f);
  return (unsigned short)((u + 0x7fffu + ((u >> 16) & 1u)) >> 16);  // RNE
}

// global -> LDS direct (wave-uniform LDS base + lane*16B; global addr per-lane)
#define AS1C(p) ((const __attribute__((address_space(1))) void*)(uintptr_t)(p))
#define AS3(p)  ((__attribute__((address_space(3))) void*)(unsigned)(uintptr_t)(p))
DEV void gload16(const void* g, void* l) {
  __builtin_amdgcn_global_load_lds(AS1C(g), AS3(l), 16, 0, 0);
}

static constexpr int B_ = 32, T_ = 1024, D_ = 1024;
static constexpr int M_ = B_ * T_;     // 32768 rows
static constexpr int N3 = 3 * D_;      // 3072 (q|k|v concat)

// ---- K0: weights fp32 -> bf16 concat [3072][1024]; biases; zero ksum ------
__global__ __launch_bounds__(256) void cvt_weights(
    const float* __restrict__ Wq, const float* __restrict__ Wk, const float* __restrict__ Wv,
    const float* __restrict__ bq, const float* __restrict__ bk, const float* __restrict__ bv,
    unsigned short* __restrict__ Wcat, float* __restrict__ bias,
    float* __restrict__ ksum)
{
  int idx = blockIdx.x * 256 + threadIdx.x;      // 786432 threads x 4 elems
  int which = idx >> 18;                          // / (1048576/4)
  int rem   = idx & 262143;
  const float* src = which == 0 ? Wq : (which == 1 ? Wk : Wv);
  f32x4 v = reinterpret_cast<const f32x4*>(src)[rem];
  uint2v p;
  p[0] = (unsigned)f2b(v[0]) | ((unsigned)f2b(v[1]) << 16);
  p[1] = (unsigned)f2b(v[2]) | ((unsigned)f2b(v[3]) << 16);
  reinterpret_cast<uint2v*>(Wcat)[idx] = p;
  if (idx < 3072) {
    const float* bsrc = idx < 1024 ? bq : (idx < 2048 ? bk : bv);
    bias[idx] = bsrc[idx & 1023];
  }
  if (idx < 32768) ksum[idx] = 0.f;   // [32 b][1024 col] partial-exp sums
}

// ---- K1: LayerNorm -> bf16 ------------------------------------------------
__global__ __launch_bounds__(256) void ln_kernel(
    const float* __restrict__ x, const float* __restrict__ g, const float* __restrict__ b,
    unsigned short* __restrict__ xn)
{
  int row = blockIdx.x;
  int tid = threadIdx.x;
  const f32x4 v = reinterpret_cast<const f32x4*>(x + (size_t)row * D_)[tid];
  float s  = v[0] + v[1] + v[2] + v[3];
  float s2 = v[0]*v[0] + v[1]*v[1] + v[2]*v[2] + v[3]*v[3];
  #pragma unroll
  for (int o = 32; o > 0; o >>= 1) { s += __shfl_down(s, o); s2 += __shfl_down(s2, o); }
  __shared__ float rs_[4], rs2_[4];
  int lane = tid & 63, wave = tid >> 6;
  if (lane == 0) { rs_[wave] = s; rs2_[wave] = s2; }
  __syncthreads();
  float S  = rs_[0] + rs_[1] + rs_[2] + rs_[3];
  float S2 = rs2_[0] + rs2_[1] + rs2_[2] + rs2_[3];
  float mu = S * (1.f / D_);
  float var = S2 * (1.f / D_) - mu * mu;
  float rstd = rsqrtf(var + 1e-5f);
  const f32x4 gg = reinterpret_cast<const f32x4*>(g)[tid];
  const f32x4 bb = reinterpret_cast<const f32x4*>(b)[tid];
  float y0 = (v[0]-mu)*rstd*gg[0] + bb[0];
  float y1 = (v[1]-mu)*rstd*gg[1] + bb[1];
  float y2 = (v[2]-mu)*rstd*gg[2] + bb[2];
  float y3 = (v[3]-mu)*rstd*gg[3] + bb[3];
  uint2v p;
  p[0] = (unsigned)f2b(y0) | ((unsigned)f2b(y1) << 16);
  p[1] = (unsigned)f2b(y2) | ((unsigned)f2b(y3) << 16);
  reinterpret_cast<uint2v*>(xn + (size_t)row * D_)[tid] = p;
}

// ---- K2: fused QKV GEMM, C[M][3072] = xn @ Wcat^T + bias (bf16 out) -------
// 256x256 tile, BK=32, R7: 2-deep LDS ring (64 KiB -> 2 blocks/CU so the
// sibling block covers the tile-end vmcnt(0)+barrier drain, m114 mechanism).
// XOR-swizzled LDS, one barrier/K-tile, setprio on MFMA clusters.
// 8 waves: 2M x 4N, 128x64 out/wave.
__global__ __launch_bounds__(512, 4) void gemm_qkv(
    const unsigned short* __restrict__ A,   // [M_][1024] bf16
    const unsigned short* __restrict__ Bm,  // [3072][1024] bf16 (B^T input form)
    const float* __restrict__ bias,         // [3072]
    unsigned short* __restrict__ C,         // [M_][3072] bf16
    float* __restrict__ ksum)               // [32][1024]
{
  __shared__ alignas(16) short lds[2 * 16384];   // 2 bufs x (A 8192 + B 8192)
  const int tid = threadIdx.x;
  constexpr int nbn = N3 / 256;            // 12
  constexpr int nwg = (M_ / 256) * nbn;    // 1536 (%8==0 -> simple swizzle ok)
  int wg = blockIdx.x;
  int swzb = (wg & 7) * (nwg >> 3) + (wg >> 3);   // XCD-aware
  int bm = swzb / nbn, bn = swzb % nbn;
  int arow = bm * 256, bcol = bn * 256;
  int lane = tid & 63, wave = tid >> 6;
  int wr = wave >> 2, wc = wave & 3;       // 2M x 4N waves
  int g = lane >> 4, r = lane & 15;

  const unsigned short* Ab = A  + (size_t)arow * 1024;
  const unsigned short* Bb = Bm + (size_t)bcol * 1024;

  // staging geometry: per round (128 rows x 32 cols = 16KB), 512 thr x 16B.
  // LDS dest linear; global source inverse-swizzled: pg = (l&3) ^ ((rho>>1)&3)
  int rho = (wave << 4) | (lane >> 2);     // 0..127 within round
  int pg  = (lane & 3) ^ ((rho >> 1) & 3);
  size_t gR0 = (size_t)rho * 1024 + pg * 8;          // rows 0..127 of tile
  size_t gR1 = (size_t)(rho + 128) * 1024 + pg * 8;  // rows 128..255
  int lofs = wave * 512;                   // shorts: wave-uniform LDS base

  #define STAGE_A(t) { short* bb0 = lds + (((t) & 1) << 14); int k2 = (t) << 5; \
    gload16(Ab + k2 + gR0, (void*)(bb0 + lofs)); \
    gload16(Ab + k2 + gR1, (void*)(bb0 + 4096 + lofs)); }
  #define STAGE_B(t) { short* bb0 = lds + (((t) & 1) << 14); int k2 = (t) << 5; \
    gload16(Bb + k2 + gR0, (void*)(bb0 + 8192 + lofs)); \
    gload16(Bb + k2 + gR1, (void*)(bb0 + 12288 + lofs)); }

  f32x4 acc[8][4] = {};
  // prologue: stage K-tile 0, wait landed
  STAGE_A(0); STAGE_B(0);
  asm volatile("s_waitcnt vmcnt(0)" ::: "memory");
  __builtin_amdgcn_s_barrier();

  for (int t = 0; t < 32; ++t) {
    const short* bufA = lds + ((t & 1) << 14);
    const short* bufB = bufA + 8192;
    // issue next-tile stage first: maximize load in-flight time
    if (t < 31) { STAGE_A(t + 1); STAGE_B(t + 1); }
    short8 a[8], bfr[4];
    #pragma unroll
    for (int ni = 0; ni < 4; ++ni) {
      int row = wc * 64 + ni * 16 + r;
      bfr[ni] = *(const short8*)(bufB + row * 32 + ((g ^ ((row >> 1) & 3)) << 3));
    }
    {
      int row = wr * 128 + r;
      a[0] = *(const short8*)(bufA + row * 32 + ((g ^ ((row >> 1) & 3)) << 3));
    }
    // pipelined clusters: issue read a[mi+1], then 4 MFMAs on a[mi]
    #pragma unroll
    for (int mi = 0; mi < 8; ++mi) {
      if (mi < 7) {
        int row = wr * 128 + (mi + 1) * 16 + r;
        a[mi + 1] = *(const short8*)(bufA + row * 32 + ((g ^ ((row >> 1) & 3)) << 3));
      }
      __builtin_amdgcn_s_setprio(1);
      #pragma unroll
      for (int ni = 0; ni < 4; ++ni)
        acc[mi][ni] = __builtin_amdgcn_mfma_f32_16x16x32_bf16(a[mi], bfr[ni], acc[mi][ni], 0, 0, 0);
      __builtin_amdgcn_s_setprio(0);
    }
    // tile end: drain next-tile loads (issued ~full tile ago) + barrier.
    // Sibling block on the CU covers this stall (2 blocks/CU).
    if (t < 31) {
      asm volatile("s_waitcnt vmcnt(0)" ::: "memory");
      __builtin_amdgcn_s_barrier();
    }
  }
  #undef STAGE_A
  #undef STAGE_B

  // ---- epilogue: bias + bf16 store, ni innermost (merge 128B lines) ------
  float bs[4];
  #pragma unroll
  for (int ni = 0; ni < 4; ++ni) bs[ni] = bias[bcol + wc * 64 + ni * 16 + r];
  bool isK = (bcol >= 1024 && bcol < 2048);   // block-uniform
  if (isK) {
    float ks[4] = {0.f, 0.f, 0.f, 0.f};
    #pragma unroll
    for (int mi = 0; mi < 8; ++mi)
      #pragma unroll
      for (int j = 0; j < 4; ++j) {
        int rowl = wr * 128 + mi * 16 + 4 * g + j;
        size_t rb = (size_t)(arow + rowl) * N3 + bcol + wc * 64 + r;
        #pragma unroll
        for (int ni = 0; ni < 4; ++ni) {
          unsigned short cv = f2b(acc[mi][ni][j] + bs[ni]);
          C[rb + ni * 16] = cv;
          ks[ni] += __expf(b2f(cv));   // exp of rounded value: matches attn
        }
      }
    int b = arow >> 10;
    #pragma unroll
    for (int ni = 0; ni < 4; ++ni) {
      float s = ks[ni];
      s += __shfl_xor(s, 16);
      s += __shfl_xor(s, 32);
      if (g == 0)
        atomicAdd(&ksum[b * 1024 + (bcol - 1024) + wc * 64 + ni * 16 + r], s);
    }
  } else {
    #pragma unroll
    for (int mi = 0; mi < 8; ++mi)
      #pragma unroll
      for (int j = 0; j < 4; ++j) {
        int rowl = wr * 128 + mi * 16 + 4 * g + j;
        size_t rb = (size_t)(arow + rowl) * N3 + bcol + wc * 64 + r;
        #pragma unroll
        for (int ni = 0; ni < 4; ++ni)
          C[rb + ni * 16] = f2b(acc[mi][ni][j] + bs[ni]);
      }
  }
}

// ---- K5: attn partials, 4-way split over T; k normalized on the fly -------
__global__ __launch_bounds__(256) void attn_kernel(
    const unsigned short* __restrict__ qkv, const float* __restrict__ ksum,
    float* __restrict__ attnP)
{
  int bid = blockIdx.x;             // 2048
  int bh = bid >> 2, tq = bid & 3;
  int b = bh >> 4, h = bh & 15;
  int tid = threadIdx.x;
  int cgrp = tid & 7, trow = tid >> 3;   // staging: 8 col-groups x 32 t-rows
  int lane = tid & 63, wave = tid >> 6;
  int g = lane >> 4, r = lane & 15;
  __shared__ alignas(16) short lK[64 * 40];   // [col dd][t] transposed, pad 40
  __shared__ alignas(16) short lV[64 * 40];   // [col ll][t]
  const unsigned short* kb = qkv + ((size_t)(b * T_ + tq * 256)) * N3 + D_     + h * 64;
  const unsigned short* vb = qkv + ((size_t)(b * T_ + tq * 256)) * N3 + 2 * D_ + h * 64;
  float inv[8];
  const float* kp = ksum + b * 1024 + h * 64 + cgrp * 8;
  #pragma unroll
  for (int j = 0; j < 8; ++j) inv[j] = 1.f / kp[j];
  f32x4 acc[4] = {};
  short8 kv = *(const short8*)(kb + (size_t)trow * N3 + cgrp * 8);
  short8 vv = *(const short8*)(vb + (size_t)trow * N3 + cgrp * 8);
  for (int tc = 0; tc < 8; ++tc) {
    __syncthreads();
    #pragma unroll
    for (int j = 0; j < 8; ++j) {
      lK[(cgrp * 8 + j) * 40 + trow] =
          (short)f2b(__expf(b2f((unsigned short)kv[j])) * inv[j]);
      lV[(cgrp * 8 + j) * 40 + trow] = vv[j];
    }
    __syncthreads();
    if (tc < 7) {   // prefetch next chunk under ds_read + MFMA
      kv = *(const short8*)(kb + (size_t)((tc + 1) * 32 + trow) * N3 + cgrp * 8);
      vv = *(const short8*)(vb + (size_t)((tc + 1) * 32 + trow) * N3 + cgrp * 8);
    }
    short8 af = *(const short8*)(lK + (16 * wave + r) * 40 + 8 * g);
    #pragma unroll
    for (int ni = 0; ni < 4; ++ni) {
      short8 bf = *(const short8*)(lV + (16 * ni + r) * 40 + 8 * g);
      acc[ni] = __builtin_amdgcn_mfma_f32_16x16x32_bf16(af, bf, acc[ni], 0, 0, 0);
    }
  }
  float* op = attnP + (size_t)bid * 4096;
  #pragma unroll
  for (int ni = 0; ni < 4; ++ni)
    #pragma unroll
    for (int j = 0; j < 4; ++j) {
      int m = 16 * wave + 4 * g + j;   // dd
      int n = 16 * ni + r;             // ll
      op[(size_t)n * 64 + m] = acc[ni][j];   // store transposed, f32
    }
}

// ---- K5b: reduce 4 T-partials -> attnT bf16 -------------------------------
__global__ __launch_bounds__(256) void attn_reduce(
    const float* __restrict__ attnP, unsigned short* __restrict__ attnT)
{
  int bh = blockIdx.x;             // 512
  int tid = threadIdx.x;
  const float* p0 = attnP + ((size_t)bh << 2) * 4096;
  unsigned short* o = attnT + (size_t)bh * 4096;
  #pragma unroll
  for (int it = 0; it < 4; ++it) {
    int i = (it * 256 + tid) * 4;
    f32x4 s  = *(const f32x4*)(p0 + i);
    f32x4 s1 = *(const f32x4*)(p0 + 4096 + i);
    f32x4 s2 = *(const f32x4*)(p0 + 8192 + i);
    f32x4 s3 = *(const f32x4*)(p0 + 12288 + i);
    s[0] += s1[0] + s2[0] + s3[0];
    s[1] += s1[1] + s2[1] + s3[1];
    s[2] += s1[2] + s2[2] + s3[2];
    s[3] += s1[3] + s2[3] + s3[3];
    short4v ov;
    ov[0] = (short)f2b(s[0]); ov[1] = (short)f2b(s[1]);
    ov[2] = (short)f2b(s[2]); ov[3] = (short)f2b(s[3]);
    *(short4v*)(o + i) = ov;
  }
}

// ---- K6: fused q-softmax + y = q_sm @ attn + residual ---------------------
__global__ __launch_bounds__(256) void out_kernel(
    const unsigned short* __restrict__ qkv, const unsigned short* __restrict__ attnT,
    const float* __restrict__ x, float* __restrict__ out)
{
  int bid = blockIdx.x;             // 4096 = 512 bh * 8 row-tiles
  int bh = bid >> 3, mt = bid & 7;
  int b = bh >> 4, h = bh & 15;
  int tid = threadIdx.x;
  int lane = tid & 63, wave = tid >> 6;
  int g = lane >> 4, r = lane & 15;
  __shared__ alignas(16) short lAT[64 * 72];  // attn^T [ll][dd], pad 72
  __shared__ float lO[128][66];               // out tile f32, pad 66
  const unsigned short* at = attnT + (size_t)bh * 4096;
  #pragma unroll
  for (int i = 0; i < 2; ++i) {
    int idx8 = (i * 256 + tid) * 8;
    int n = idx8 >> 6, kk0 = idx8 & 63;
    *(short8*)(lAT + n * 72 + kk0) = *(const short8*)(at + idx8);
  }
  __syncthreads();
  short8 bt[4][2];
  #pragma unroll
  for (int ni = 0; ni < 4; ++ni)
    #pragma unroll
    for (int kc = 0; kc < 2; ++kc)
      bt[ni][kc] = *(const short8*)(lAT + (16 * ni + r) * 72 + kc * 32 + 8 * g);
  int rowbase = mt * 128 + 32 * wave;
  const unsigned short* qb = qkv + (size_t)(b * T_ + rowbase) * N3 + h * 64;
  short8 aq[2][2];
  #pragma unroll
  for (int mi = 0; mi < 2; ++mi) {
    float qe[16];
    float s = 0.f;
    #pragma unroll
    for (int kc = 0; kc < 2; ++kc) {
      short8 qa = *(const short8*)(qb + (size_t)(16 * mi + r) * N3 + kc * 32 + 8 * g);
      #pragma unroll
      for (int j = 0; j < 8; ++j) {
        float e = __expf(b2f((unsigned short)qa[j]));
        qe[kc * 8 + j] = e;
        s += e;
      }
    }
    s += __shfl_xor(s, 16);
    s += __shfl_xor(s, 32);
    float inv = 1.f / s;
    #pragma unroll
    for (int kc = 0; kc < 2; ++kc) {
      short8 t8;
      #pragma unroll
      for (int j = 0; j < 8; ++j) t8[j] = (short)f2b(qe[kc * 8 + j] * inv);
      aq[mi][kc] = t8;
    }
  }
  f32x4 acc[2][4] = {};
  #pragma unroll
  for (int mi = 0; mi < 2; ++mi)
    #pragma unroll
    for (int kc = 0; kc < 2; ++kc)
      #pragma unroll
      for (int ni = 0; ni < 4; ++ni)
        acc[mi][ni] = __builtin_amdgcn_mfma_f32_16x16x32_bf16(aq[mi][kc], bt[ni][kc], acc[mi][ni], 0, 0, 0);
  // stage acc to LDS (2-way-max bank aliasing with pad 66)
  #pragma unroll
  for (int mi = 0; mi < 2; ++mi)
    #pragma unroll
    for (int ni = 0; ni < 4; ++ni)
      #pragma unroll
      for (int j = 0; j < 4; ++j)
        lO[32 * wave + 16 * mi + 4 * g + j][16 * ni + r] = acc[mi][ni][j];
  __syncthreads();
  // cooperative coalesced add+store: 16 threads/row, f32x4 each
  int rr = tid >> 4, c4 = (tid & 15) << 2;
  #pragma unroll
  for (int p = 0; p < 8; ++p) {
    int rowl = p * 16 + rr;
    size_t gi = ((size_t)(b * T_ + mt * 128 + rowl) << 10) + h * 64 + c4;
    f32x4 xv = *(const f32x4*)(x + gi);
    f32x4 ov;
    ov[0] = xv[0] + lO[rowl][c4];
    ov[1] = xv[1] + lO[rowl][c4 + 1];
    ov[2] = xv[2] + lO[rowl][c4 + 2];
    ov[3] = xv[3] + lO[rowl][c4 + 3];
    *(f32x4*)(out + gi) = ov;
  }
}

extern "C" void kernel_launch(void* const* d_in, const int* in_sizes, int n_in,
                              void* d_out, int out_size, void* d_ws, size_t ws_size,
                              hipStream_t stream) {
  const float* x   = (const float*)d_in[0];
  const float* lng = (const float*)d_in[1];
  const float* lnb = (const float*)d_in[2];
  const float* Wq  = (const float*)d_in[3];
  const float* bq  = (const float*)d_in[4];
  const float* Wk  = (const float*)d_in[5];
  const float* bk  = (const float*)d_in[6];
  const float* Wv  = (const float*)d_in[7];
  const float* bv  = (const float*)d_in[8];
  float* out = (float*)d_out;
  char* ws = (char*)d_ws;
  // ws layout (bytes), 256-aligned:
  unsigned short* Wcat  = (unsigned short*)(ws + 0);          //   6,291,456
  float*          bias  = (float*)         (ws + 6291456);    //      12,288
  unsigned short* xn    = (unsigned short*)(ws + 6303744);    //  67,108,864
  unsigned short* qkv   = (unsigned short*)(ws + 73412608);   // 201,326,592
  unsigned short* attnT = (unsigned short*)(ws + 274739200);  //   4,194,304
  // attn f32 partials reuse xn space (dead after gemm_qkv): 33.5 MB
  float* attnP = (float*)xn;
  // k-colsum scratch lives in d_out's first 128KB: zeroed by cvt_weights,
  // accumulated by gemm epilogue, read by attn, then fully overwritten by
  // out_kernel (which rewrites every element of d_out).
  float* ksum = (float*)d_out;
  cvt_weights<<<3072,  256, 0, stream>>>(Wq, Wk, Wv, bq, bk, bv, Wcat, bias, ksum);
  ln_kernel  <<<M_,    256, 0, stream>>>(x, lng, lnb, xn);
  gemm_qkv   <<<1536,  512, 0, stream>>>(xn, Wcat, bias, qkv, ksum);
  attn_kernel<<<2048,  256, 0, stream>>>(qkv, ksum, attnP);
  attn_reduce<<<512,   256, 0, stream>>>(attnP, attnT);
  out_kernel <<<4096,  256, 0, stream>>>(qkv, attnT, x, out);
}

// Round 9
// 376.606 us; speedup vs baseline: 3.7568x; 3.7568x over previous
//
#include <hip/hip_runtime.h>
#include <stdint.h>

typedef __attribute__((ext_vector_type(4))) float  f32x4;
typedef __attribute__((ext_vector_type(8))) short  short8;
typedef __attribute__((ext_vector_type(4))) short  short4v;
typedef __attribute__((ext_vector_type(2))) unsigned int uint2v;

#define DEV __device__ __forceinline__

DEV float b2f(unsigned short u) { return __uint_as_float(((unsigned)u) << 16); }
DEV unsigned short f2b(float f) {
  unsigned u = __float_as_uint(f);
  return (unsigned short)((u + 0x7fffu + ((u >> 16) & 1u)) >> 16);  // RNE
}

// global -> LDS direct (wave-uniform LDS base + lane*16B; global addr per-lane)
#define AS1C(p) ((const __attribute__((address_space(1))) void*)(uintptr_t)(p))
#define AS3(p)  ((__attribute__((address_space(3))) void*)(unsigned)(uintptr_t)(p))
DEV void gload16(const void* g, void* l) {
  __builtin_amdgcn_global_load_lds(AS1C(g), AS3(l), 16, 0, 0);
}

static constexpr int B_ = 32, T_ = 1024, D_ = 1024;
static constexpr int M_ = B_ * T_;     // 32768 rows
static constexpr int N3 = 3 * D_;      // 3072 (q|k|v concat)

// ---- K0: weights fp32 -> bf16 concat [3072][1024]; biases; zero ksum ------
__global__ __launch_bounds__(256) void cvt_weights(
    const float* __restrict__ Wq, const float* __restrict__ Wk, const float* __restrict__ Wv,
    const float* __restrict__ bq, const float* __restrict__ bk, const float* __restrict__ bv,
    unsigned short* __restrict__ Wcat, float* __restrict__ bias,
    float* __restrict__ ksum)
{
  int idx = blockIdx.x * 256 + threadIdx.x;      // 786432 threads x 4 elems
  int which = idx >> 18;                          // / (1048576/4)
  int rem   = idx & 262143;
  const float* src = which == 0 ? Wq : (which == 1 ? Wk : Wv);
  f32x4 v = reinterpret_cast<const f32x4*>(src)[rem];
  uint2v p;
  p[0] = (unsigned)f2b(v[0]) | ((unsigned)f2b(v[1]) << 16);
  p[1] = (unsigned)f2b(v[2]) | ((unsigned)f2b(v[3]) << 16);
  reinterpret_cast<uint2v*>(Wcat)[idx] = p;
  if (idx < 3072) {
    const float* bsrc = idx < 1024 ? bq : (idx < 2048 ? bk : bv);
    bias[idx] = bsrc[idx & 1023];
  }
  if (idx < 32768) ksum[idx] = 0.f;   // [32 b][1024 col] partial-exp sums
}

// ---- K1: LayerNorm -> bf16 ------------------------------------------------
__global__ __launch_bounds__(256) void ln_kernel(
    const float* __restrict__ x, const float* __restrict__ g, const float* __restrict__ b,
    unsigned short* __restrict__ xn)
{
  int row = blockIdx.x;
  int tid = threadIdx.x;
  const f32x4 v = reinterpret_cast<const f32x4*>(x + (size_t)row * D_)[tid];
  float s  = v[0] + v[1] + v[2] + v[3];
  float s2 = v[0]*v[0] + v[1]*v[1] + v[2]*v[2] + v[3]*v[3];
  #pragma unroll
  for (int o = 32; o > 0; o >>= 1) { s += __shfl_down(s, o); s2 += __shfl_down(s2, o); }
  __shared__ float rs_[4], rs2_[4];
  int lane = tid & 63, wave = tid >> 6;
  if (lane == 0) { rs_[wave] = s; rs2_[wave] = s2; }
  __syncthreads();
  float S  = rs_[0] + rs_[1] + rs_[2] + rs_[3];
  float S2 = rs2_[0] + rs2_[1] + rs2_[2] + rs2_[3];
  float mu = S * (1.f / D_);
  float var = S2 * (1.f / D_) - mu * mu;
  float rstd = rsqrtf(var + 1e-5f);
  const f32x4 gg = reinterpret_cast<const f32x4*>(g)[tid];
  const f32x4 bb = reinterpret_cast<const f32x4*>(b)[tid];
  float y0 = (v[0]-mu)*rstd*gg[0] + bb[0];
  float y1 = (v[1]-mu)*rstd*gg[1] + bb[1];
  float y2 = (v[2]-mu)*rstd*gg[2] + bb[2];
  float y3 = (v[3]-mu)*rstd*gg[3] + bb[3];
  uint2v p;
  p[0] = (unsigned)f2b(y0) | ((unsigned)f2b(y1) << 16);
  p[1] = (unsigned)f2b(y2) | ((unsigned)f2b(y3) << 16);
  reinterpret_cast<uint2v*>(xn + (size_t)row * D_)[tid] = p;
}

// ---- K2: fused QKV GEMM, C[M][3072] = xn @ Wcat^T + bias (bf16 out) -------
// R6 known-good: 256x256 tile, BK=32, 4-deep LDS K-tile ring (128 KiB),
// counted vmcnt(8), XOR-swizzled LDS, ONE barrier/K-tile, merged MFMA phase,
// setprio on MFMA cluster. 8 waves: 2M x 4N, 128x64 out/wave.
// NOTE (R8 lesson): do NOT raise min-waves/EU — acc alone is 128 regs;
// a 128-reg cap spills accumulators to scratch (2.5 GB FETCH, 6x slower).
__global__ __launch_bounds__(512, 2) void gemm_qkv(
    const unsigned short* __restrict__ A,   // [M_][1024] bf16
    const unsigned short* __restrict__ Bm,  // [3072][1024] bf16 (B^T input form)
    const float* __restrict__ bias,         // [3072]
    unsigned short* __restrict__ C,         // [M_][3072] bf16
    float* __restrict__ ksum)               // [32][1024]
{
  __shared__ alignas(16) short lds[4 * 16384];   // 4 bufs x (A 8192 + B 8192)
  const int tid = threadIdx.x;
  constexpr int nbn = N3 / 256;            // 12
  constexpr int nwg = (M_ / 256) * nbn;    // 1536 (%8==0 -> simple swizzle ok)
  int wg = blockIdx.x;
  int swzb = (wg & 7) * (nwg >> 3) + (wg >> 3);   // XCD-aware
  int bm = swzb / nbn, bn = swzb % nbn;
  int arow = bm * 256, bcol = bn * 256;
  int lane = tid & 63, wave = tid >> 6;
  int wr = wave >> 2, wc = wave & 3;       // 2M x 4N waves
  int g = lane >> 4, r = lane & 15;

  const unsigned short* Ab = A  + (size_t)arow * 1024;
  const unsigned short* Bb = Bm + (size_t)bcol * 1024;

  // staging geometry: per round (128 rows x 32 cols = 16KB), 512 thr x 16B.
  // LDS dest linear; global source inverse-swizzled: pg = (l&3) ^ ((rho>>1)&3)
  int rho = (wave << 4) | (lane >> 2);     // 0..127 within round
  int pg  = (lane & 3) ^ ((rho >> 1) & 3);
  size_t gR0 = (size_t)rho * 1024 + pg * 8;          // rows 0..127 of tile
  size_t gR1 = (size_t)(rho + 128) * 1024 + pg * 8;  // rows 128..255
  int lofs = wave * 512;                   // shorts: wave-uniform LDS base

  #define STAGE_A(t) { short* bb0 = lds + (((t) & 3) << 14); int k2 = (t) << 5; \
    gload16(Ab + k2 + gR0, (void*)(bb0 + lofs)); \
    gload16(Ab + k2 + gR1, (void*)(bb0 + 4096 + lofs)); }
  #define STAGE_B(t) { short* bb0 = lds + (((t) & 3) << 14); int k2 = (t) << 5; \
    gload16(Bb + k2 + gR0, (void*)(bb0 + 8192 + lofs)); \
    gload16(Bb + k2 + gR1, (void*)(bb0 + 12288 + lofs)); }

  f32x4 acc[8][4] = {};
  // prologue: stage K-tiles 0,1,2 (12 loads/thread), wait tile 0 landed
  STAGE_A(0); STAGE_B(0);
  STAGE_A(1); STAGE_B(1);
  STAGE_A(2); STAGE_B(2);
  asm volatile("s_waitcnt vmcnt(8)" ::: "memory");
  __builtin_amdgcn_s_barrier();

  for (int t = 0; t < 32; ++t) {
    const short* bufA = lds + ((t & 3) << 14);
    const short* bufB = bufA + 8192;
    short8 a[8], bfr[4];
    #pragma unroll
    for (int mi = 0; mi < 8; ++mi) {
      int row = wr * 128 + mi * 16 + r;
      a[mi] = *(const short8*)(bufA + row * 32 + ((g ^ ((row >> 1) & 3)) << 3));
    }
    #pragma unroll
    for (int ni = 0; ni < 4; ++ni) {
      int row = wc * 64 + ni * 16 + r;
      bfr[ni] = *(const short8*)(bufB + row * 32 + ((g ^ ((row >> 1) & 3)) << 3));
    }
    if (t < 29) { STAGE_A(t + 3); STAGE_B(t + 3); }
    __builtin_amdgcn_s_setprio(1);
    #pragma unroll
    for (int mi = 0; mi < 8; ++mi)
      #pragma unroll
      for (int ni = 0; ni < 4; ++ni)
        acc[mi][ni] = __builtin_amdgcn_mfma_f32_16x16x32_bf16(a[mi], bfr[ni], acc[mi][ni], 0, 0, 0);
    __builtin_amdgcn_s_setprio(0);
    // ---- tile end: counted vmcnt (never 0 in steady state) + barrier ----
    if (t < 29)       { asm volatile("s_waitcnt vmcnt(8)" ::: "memory"); }
    else if (t == 29) { asm volatile("s_waitcnt vmcnt(4)" ::: "memory"); }
    else if (t == 30) { asm volatile("s_waitcnt vmcnt(0)" ::: "memory"); }
    __builtin_amdgcn_s_barrier();
  }
  #undef STAGE_A
  #undef STAGE_B

  // ---- epilogue: bias + bf16 store, ni innermost (merge 128B lines) ------
  float bs[4];
  #pragma unroll
  for (int ni = 0; ni < 4; ++ni) bs[ni] = bias[bcol + wc * 64 + ni * 16 + r];
  bool isK = (bcol >= 1024 && bcol < 2048);   // block-uniform
  if (isK) {
    float ks[4] = {0.f, 0.f, 0.f, 0.f};
    #pragma unroll
    for (int mi = 0; mi < 8; ++mi)
      #pragma unroll
      for (int j = 0; j < 4; ++j) {
        int rowl = wr * 128 + mi * 16 + 4 * g + j;
        size_t rb = (size_t)(arow + rowl) * N3 + bcol + wc * 64 + r;
        #pragma unroll
        for (int ni = 0; ni < 4; ++ni) {
          unsigned short cv = f2b(acc[mi][ni][j] + bs[ni]);
          C[rb + ni * 16] = cv;
          ks[ni] += __expf(b2f(cv));   // exp of rounded value: matches attn
        }
      }
    int b = arow >> 10;
    #pragma unroll
    for (int ni = 0; ni < 4; ++ni) {
      float s = ks[ni];
      s += __shfl_xor(s, 16);
      s += __shfl_xor(s, 32);
      if (g == 0)
        atomicAdd(&ksum[b * 1024 + (bcol - 1024) + wc * 64 + ni * 16 + r], s);
    }
  } else {
    #pragma unroll
    for (int mi = 0; mi < 8; ++mi)
      #pragma unroll
      for (int j = 0; j < 4; ++j) {
        int rowl = wr * 128 + mi * 16 + 4 * g + j;
        size_t rb = (size_t)(arow + rowl) * N3 + bcol + wc * 64 + r;
        #pragma unroll
        for (int ni = 0; ni < 4; ++ni)
          C[rb + ni * 16] = f2b(acc[mi][ni][j] + bs[ni]);
      }
  }
}

// ---- K5: attn partials, 4-way split over T; k normalized on the fly -------
__global__ __launch_bounds__(256) void attn_kernel(
    const unsigned short* __restrict__ qkv, const float* __restrict__ ksum,
    float* __restrict__ attnP)
{
  int bid = blockIdx.x;             // 2048
  int bh = bid >> 2, tq = bid & 3;
  int b = bh >> 4, h = bh & 15;
  int tid = threadIdx.x;
  int cgrp = tid & 7, trow = tid >> 3;   // staging: 8 col-groups x 32 t-rows
  int lane = tid & 63, wave = tid >> 6;
  int g = lane >> 4, r = lane & 15;
  __shared__ alignas(16) short lK[64 * 40];   // [col dd][t] transposed, pad 40
  __shared__ alignas(16) short lV[64 * 40];   // [col ll][t]
  const unsigned short* kb = qkv + ((size_t)(b * T_ + tq * 256)) * N3 + D_     + h * 64;
  const unsigned short* vb = qkv + ((size_t)(b * T_ + tq * 256)) * N3 + 2 * D_ + h * 64;
  float inv[8];
  const float* kp = ksum + b * 1024 + h * 64 + cgrp * 8;
  #pragma unroll
  for (int j = 0; j < 8; ++j) inv[j] = 1.f / kp[j];
  f32x4 acc[4] = {};
  short8 kv = *(const short8*)(kb + (size_t)trow * N3 + cgrp * 8);
  short8 vv = *(const short8*)(vb + (size_t)trow * N3 + cgrp * 8);
  for (int tc = 0; tc < 8; ++tc) {
    __syncthreads();
    #pragma unroll
    for (int j = 0; j < 8; ++j) {
      lK[(cgrp * 8 + j) * 40 + trow] =
          (short)f2b(__expf(b2f((unsigned short)kv[j])) * inv[j]);
      lV[(cgrp * 8 + j) * 40 + trow] = vv[j];
    }
    __syncthreads();
    if (tc < 7) {   // prefetch next chunk under ds_read + MFMA
      kv = *(const short8*)(kb + (size_t)((tc + 1) * 32 + trow) * N3 + cgrp * 8);
      vv = *(const short8*)(vb + (size_t)((tc + 1) * 32 + trow) * N3 + cgrp * 8);
    }
    short8 af = *(const short8*)(lK + (16 * wave + r) * 40 + 8 * g);
    #pragma unroll
    for (int ni = 0; ni < 4; ++ni) {
      short8 bf = *(const short8*)(lV + (16 * ni + r) * 40 + 8 * g);
      acc[ni] = __builtin_amdgcn_mfma_f32_16x16x32_bf16(af, bf, acc[ni], 0, 0, 0);
    }
  }
  float* op = attnP + (size_t)bid * 4096;
  #pragma unroll
  for (int ni = 0; ni < 4; ++ni)
    #pragma unroll
    for (int j = 0; j < 4; ++j) {
      int m = 16 * wave + 4 * g + j;   // dd
      int n = 16 * ni + r;             // ll
      op[(size_t)n * 64 + m] = acc[ni][j];   // store transposed, f32
    }
}

// ---- K5b: reduce 4 T-partials -> attnT bf16 -------------------------------
__global__ __launch_bounds__(256) void attn_reduce(
    const float* __restrict__ attnP, unsigned short* __restrict__ attnT)
{
  int bh = blockIdx.x;             // 512
  int tid = threadIdx.x;
  const float* p0 = attnP + ((size_t)bh << 2) * 4096;
  unsigned short* o = attnT + (size_t)bh * 4096;
  #pragma unroll
  for (int it = 0; it < 4; ++it) {
    int i = (it * 256 + tid) * 4;
    f32x4 s  = *(const f32x4*)(p0 + i);
    f32x4 s1 = *(const f32x4*)(p0 + 4096 + i);
    f32x4 s2 = *(const f32x4*)(p0 + 8192 + i);
    f32x4 s3 = *(const f32x4*)(p0 + 12288 + i);
    s[0] += s1[0] + s2[0] + s3[0];
    s[1] += s1[1] + s2[1] + s3[1];
    s[2] += s1[2] + s2[2] + s3[2];
    s[3] += s1[3] + s2[3] + s3[3];
    short4v ov;
    ov[0] = (short)f2b(s[0]); ov[1] = (short)f2b(s[1]);
    ov[2] = (short)f2b(s[2]); ov[3] = (short)f2b(s[3]);
    *(short4v*)(o + i) = ov;
  }
}

// ---- K6: fused q-softmax + y = q_sm @ attn + residual ---------------------
__global__ __launch_bounds__(256) void out_kernel(
    const unsigned short* __restrict__ qkv, const unsigned short* __restrict__ attnT,
    const float* __restrict__ x, float* __restrict__ out)
{
  int bid = blockIdx.x;             // 4096 = 512 bh * 8 row-tiles
  int bh = bid >> 3, mt = bid & 7;
  int b = bh >> 4, h = bh & 15;
  int tid = threadIdx.x;
  int lane = tid & 63, wave = tid >> 6;
  int g = lane >> 4, r = lane & 15;
  __shared__ alignas(16) short lAT[64 * 72];  // attn^T [ll][dd], pad 72
  __shared__ float lO[128][66];               // out tile f32, pad 66
  const unsigned short* at = attnT + (size_t)bh * 4096;
  #pragma unroll
  for (int i = 0; i < 2; ++i) {
    int idx8 = (i * 256 + tid) * 8;
    int n = idx8 >> 6, kk0 = idx8 & 63;
    *(short8*)(lAT + n * 72 + kk0) = *(const short8*)(at + idx8);
  }
  __syncthreads();
  short8 bt[4][2];
  #pragma unroll
  for (int ni = 0; ni < 4; ++ni)
    #pragma unroll
    for (int kc = 0; kc < 2; ++kc)
      bt[ni][kc] = *(const short8*)(lAT + (16 * ni + r) * 72 + kc * 32 + 8 * g);
  int rowbase = mt * 128 + 32 * wave;
  const unsigned short* qb = qkv + (size_t)(b * T_ + rowbase) * N3 + h * 64;
  short8 aq[2][2];
  #pragma unroll
  for (int mi = 0; mi < 2; ++mi) {
    float qe[16];
    float s = 0.f;
    #pragma unroll
    for (int kc = 0; kc < 2; ++kc) {
      short8 qa = *(const short8*)(qb + (size_t)(16 * mi + r) * N3 + kc * 32 + 8 * g);
      #pragma unroll
      for (int j = 0; j < 8; ++j) {
        float e = __expf(b2f((unsigned short)qa[j]));
        qe[kc * 8 + j] = e;
        s += e;
      }
    }
    s += __shfl_xor(s, 16);
    s += __shfl_xor(s, 32);
    float inv = 1.f / s;
    #pragma unroll
    for (int kc = 0; kc < 2; ++kc) {
      short8 t8;
      #pragma unroll
      for (int j = 0; j < 8; ++j) t8[j] = (short)f2b(qe[kc * 8 + j] * inv);
      aq[mi][kc] = t8;
    }
  }
  f32x4 acc[2][4] = {};
  #pragma unroll
  for (int mi = 0; mi < 2; ++mi)
    #pragma unroll
    for (int kc = 0; kc < 2; ++kc)
      #pragma unroll
      for (int ni = 0; ni < 4; ++ni)
        acc[mi][ni] = __builtin_amdgcn_mfma_f32_16x16x32_bf16(aq[mi][kc], bt[ni][kc], acc[mi][ni], 0, 0, 0);
  // stage acc to LDS (2-way-max bank aliasing with pad 66)
  #pragma unroll
  for (int mi = 0; mi < 2; ++mi)
    #pragma unroll
    for (int ni = 0; ni < 4; ++ni)
      #pragma unroll
      for (int j = 0; j < 4; ++j)
        lO[32 * wave + 16 * mi + 4 * g + j][16 * ni + r] = acc[mi][ni][j];
  __syncthreads();
  // cooperative coalesced add+store: 16 threads/row, f32x4 each
  int rr = tid >> 4, c4 = (tid & 15) << 2;
  #pragma unroll
  for (int p = 0; p < 8; ++p) {
    int rowl = p * 16 + rr;
    size_t gi = ((size_t)(b * T_ + mt * 128 + rowl) << 10) + h * 64 + c4;
    f32x4 xv = *(const f32x4*)(x + gi);
    f32x4 ov;
    ov[0] = xv[0] + lO[rowl][c4];
    ov[1] = xv[1] + lO[rowl][c4 + 1];
    ov[2] = xv[2] + lO[rowl][c4 + 2];
    ov[3] = xv[3] + lO[rowl][c4 + 3];
    *(f32x4*)(out + gi) = ov;
  }
}

extern "C" void kernel_launch(void* const* d_in, const int* in_sizes, int n_in,
                              void* d_out, int out_size, void* d_ws, size_t ws_size,
                              hipStream_t stream) {
  const float* x   = (const float*)d_in[0];
  const float* lng = (const float*)d_in[1];
  const float* lnb = (const float*)d_in[2];
  const float* Wq  = (const float*)d_in[3];
  const float* bq  = (const float*)d_in[4];
  const float* Wk  = (const float*)d_in[5];
  const float* bk  = (const float*)d_in[6];
  const float* Wv  = (const float*)d_in[7];
  const float* bv  = (const float*)d_in[8];
  float* out = (float*)d_out;
  char* ws = (char*)d_ws;
  // ws layout (bytes), 256-aligned:
  unsigned short* Wcat  = (unsigned short*)(ws + 0);          //   6,291,456
  float*          bias  = (float*)         (ws + 6291456);    //      12,288
  unsigned short* xn    = (unsigned short*)(ws + 6303744);    //  67,108,864
  unsigned short* qkv   = (unsigned short*)(ws + 73412608);   // 201,326,592
  unsigned short* attnT = (unsigned short*)(ws + 274739200);  //   4,194,304
  // attn f32 partials reuse xn space (dead after gemm_qkv): 33.5 MB
  float* attnP = (float*)xn;
  // k-colsum scratch lives in d_out's first 128KB: zeroed by cvt_weights,
  // accumulated by gemm epilogue, read by attn, then fully overwritten by
  // out_kernel (which rewrites every element of d_out).
  float* ksum = (float*)d_out;
  cvt_weights<<<3072,  256, 0, stream>>>(Wq, Wk, Wv, bq, bk, bv, Wcat, bias, ksum);
  ln_kernel  <<<M_,    256, 0, stream>>>(x, lng, lnb, xn);
  gemm_qkv   <<<1536,  512, 0, stream>>>(xn, Wcat, bias, qkv, ksum);
  attn_kernel<<<2048,  256, 0, stream>>>(qkv, ksum, attnP);
  attn_reduce<<<512,   256, 0, stream>>>(attnP, attnT);
  out_kernel <<<4096,  256, 0, stream>>>(qkv, attnT, x, out);
}

// Round 10
// 374.843 us; speedup vs baseline: 3.7745x; 1.0047x over previous
//
#include <hip/hip_runtime.h>
#include <stdint.h>

typedef __attribute__((ext_vector_type(4))) float  f32x4;
typedef __attribute__((ext_vector_type(8))) short  short8;
typedef __attribute__((ext_vector_type(4))) short  short4v;
typedef __attribute__((ext_vector_type(2))) unsigned int uint2v;

#define DEV __device__ __forceinline__

DEV float b2f(unsigned short u) { return __uint_as_float(((unsigned)u) << 16); }
DEV unsigned short f2b(float f) {
  unsigned u = __float_as_uint(f);
  return (unsigned short)((u + 0x7fffu + ((u >> 16) & 1u)) >> 16);  // RNE
}

// global -> LDS direct (wave-uniform LDS base + lane*16B; global addr per-lane)
#define AS1C(p) ((const __attribute__((address_space(1))) void*)(uintptr_t)(p))
#define AS3(p)  ((__attribute__((address_space(3))) void*)(unsigned)(uintptr_t)(p))
DEV void gload16(const void* g, void* l) {
  __builtin_amdgcn_global_load_lds(AS1C(g), AS3(l), 16, 0, 0);
}

static constexpr int B_ = 32, T_ = 1024, D_ = 1024;
static constexpr int M_ = B_ * T_;     // 32768 rows
static constexpr int N3 = 3 * D_;      // 3072 (q|k|v concat)

// ---- K0: merged prep: weights->bf16 concat + biases + ksum zero + LN ------
// blocks [0,3072): cvt; blocks [3072, 3072+32768): layernorm row (bid-3072).
__global__ __launch_bounds__(256) void prep_kernel(
    const float* __restrict__ Wq, const float* __restrict__ Wk, const float* __restrict__ Wv,
    const float* __restrict__ bq, const float* __restrict__ bk, const float* __restrict__ bv,
    const float* __restrict__ x, const float* __restrict__ lng, const float* __restrict__ lnb,
    unsigned short* __restrict__ Wcat, float* __restrict__ bias,
    float* __restrict__ ksum, unsigned short* __restrict__ xn)
{
  int bid = blockIdx.x;
  int tid = threadIdx.x;
  if (bid < 3072) {
    int idx = bid * 256 + tid;                    // 786432 threads x 4 elems
    int which = idx >> 18;
    int rem   = idx & 262143;
    const float* src = which == 0 ? Wq : (which == 1 ? Wk : Wv);
    f32x4 v = reinterpret_cast<const f32x4*>(src)[rem];
    uint2v p;
    p[0] = (unsigned)f2b(v[0]) | ((unsigned)f2b(v[1]) << 16);
    p[1] = (unsigned)f2b(v[2]) | ((unsigned)f2b(v[3]) << 16);
    reinterpret_cast<uint2v*>(Wcat)[idx] = p;
    if (idx < 3072) {
      const float* bsrc = idx < 1024 ? bq : (idx < 2048 ? bk : bv);
      bias[idx] = bsrc[idx & 1023];
    }
    if (idx < 32768) ksum[idx] = 0.f;   // [32 b][1024 col] partial-exp sums
    return;
  }
  int row = bid - 3072;
  const f32x4 v = reinterpret_cast<const f32x4*>(x + (size_t)row * D_)[tid];
  float s  = v[0] + v[1] + v[2] + v[3];
  float s2 = v[0]*v[0] + v[1]*v[1] + v[2]*v[2] + v[3]*v[3];
  #pragma unroll
  for (int o = 32; o > 0; o >>= 1) { s += __shfl_down(s, o); s2 += __shfl_down(s2, o); }
  __shared__ float rs_[4], rs2_[4];
  int lane = tid & 63, wave = tid >> 6;
  if (lane == 0) { rs_[wave] = s; rs2_[wave] = s2; }
  __syncthreads();
  float S  = rs_[0] + rs_[1] + rs_[2] + rs_[3];
  float S2 = rs2_[0] + rs2_[1] + rs2_[2] + rs2_[3];
  float mu = S * (1.f / D_);
  float var = S2 * (1.f / D_) - mu * mu;
  float rstd = rsqrtf(var + 1e-5f);
  const f32x4 gg = reinterpret_cast<const f32x4*>(lng)[tid];
  const f32x4 bb = reinterpret_cast<const f32x4*>(lnb)[tid];
  float y0 = (v[0]-mu)*rstd*gg[0] + bb[0];
  float y1 = (v[1]-mu)*rstd*gg[1] + bb[1];
  float y2 = (v[2]-mu)*rstd*gg[2] + bb[2];
  float y3 = (v[3]-mu)*rstd*gg[3] + bb[3];
  uint2v p;
  p[0] = (unsigned)f2b(y0) | ((unsigned)f2b(y1) << 16);
  p[1] = (unsigned)f2b(y2) | ((unsigned)f2b(y3) << 16);
  reinterpret_cast<uint2v*>(xn + (size_t)row * D_)[tid] = p;
}

// ---- K2: fused QKV GEMM, C[M][3072] = xn @ Wcat^T + bias (bf16 out) -------
// R6 known-good: 256x256 tile, BK=32, 4-deep LDS K-tile ring (128 KiB),
// counted vmcnt(8), XOR-swizzled LDS, ONE barrier/K-tile, merged MFMA phase,
// setprio on MFMA cluster. 8 waves: 2M x 4N, 128x64 out/wave.
// NOTE (R8 lesson): do NOT raise min-waves/EU — acc alone is 128 regs;
// a 128-reg cap spills accumulators to scratch (2.5 GB FETCH, 6x slower).
__global__ __launch_bounds__(512, 2) void gemm_qkv(
    const unsigned short* __restrict__ A,   // [M_][1024] bf16
    const unsigned short* __restrict__ Bm,  // [3072][1024] bf16 (B^T input form)
    const float* __restrict__ bias,         // [3072]
    unsigned short* __restrict__ C,         // [M_][3072] bf16
    float* __restrict__ ksum)               // [32][1024]
{
  __shared__ alignas(16) short lds[4 * 16384];   // 4 bufs x (A 8192 + B 8192)
  const int tid = threadIdx.x;
  constexpr int nbn = N3 / 256;            // 12
  constexpr int nwg = (M_ / 256) * nbn;    // 1536 (%8==0 -> simple swizzle ok)
  int wg = blockIdx.x;
  int swzb = (wg & 7) * (nwg >> 3) + (wg >> 3);   // XCD-aware
  int bm = swzb / nbn, bn = swzb % nbn;
  int arow = bm * 256, bcol = bn * 256;
  int lane = tid & 63, wave = tid >> 6;
  int wr = wave >> 2, wc = wave & 3;       // 2M x 4N waves
  int g = lane >> 4, r = lane & 15;

  const unsigned short* Ab = A  + (size_t)arow * 1024;
  const unsigned short* Bb = Bm + (size_t)bcol * 1024;

  // staging geometry: per round (128 rows x 32 cols = 16KB), 512 thr x 16B.
  // LDS dest linear; global source inverse-swizzled: pg = (l&3) ^ ((rho>>1)&3)
  int rho = (wave << 4) | (lane >> 2);     // 0..127 within round
  int pg  = (lane & 3) ^ ((rho >> 1) & 3);
  size_t gR0 = (size_t)rho * 1024 + pg * 8;          // rows 0..127 of tile
  size_t gR1 = (size_t)(rho + 128) * 1024 + pg * 8;  // rows 128..255
  int lofs = wave * 512;                   // shorts: wave-uniform LDS base

  #define STAGE_A(t) { short* bb0 = lds + (((t) & 3) << 14); int k2 = (t) << 5; \
    gload16(Ab + k2 + gR0, (void*)(bb0 + lofs)); \
    gload16(Ab + k2 + gR1, (void*)(bb0 + 4096 + lofs)); }
  #define STAGE_B(t) { short* bb0 = lds + (((t) & 3) << 14); int k2 = (t) << 5; \
    gload16(Bb + k2 + gR0, (void*)(bb0 + 8192 + lofs)); \
    gload16(Bb + k2 + gR1, (void*)(bb0 + 12288 + lofs)); }

  f32x4 acc[8][4] = {};
  // prologue: stage K-tiles 0,1,2 (12 loads/thread), wait tile 0 landed
  STAGE_A(0); STAGE_B(0);
  STAGE_A(1); STAGE_B(1);
  STAGE_A(2); STAGE_B(2);
  asm volatile("s_waitcnt vmcnt(8)" ::: "memory");
  __builtin_amdgcn_s_barrier();

  for (int t = 0; t < 32; ++t) {
    const short* bufA = lds + ((t & 3) << 14);
    const short* bufB = bufA + 8192;
    short8 a[8], bfr[4];
    #pragma unroll
    for (int mi = 0; mi < 8; ++mi) {
      int row = wr * 128 + mi * 16 + r;
      a[mi] = *(const short8*)(bufA + row * 32 + ((g ^ ((row >> 1) & 3)) << 3));
    }
    #pragma unroll
    for (int ni = 0; ni < 4; ++ni) {
      int row = wc * 64 + ni * 16 + r;
      bfr[ni] = *(const short8*)(bufB + row * 32 + ((g ^ ((row >> 1) & 3)) << 3));
    }
    if (t < 29) { STAGE_A(t + 3); STAGE_B(t + 3); }
    __builtin_amdgcn_s_setprio(1);
    #pragma unroll
    for (int mi = 0; mi < 8; ++mi)
      #pragma unroll
      for (int ni = 0; ni < 4; ++ni)
        acc[mi][ni] = __builtin_amdgcn_mfma_f32_16x16x32_bf16(a[mi], bfr[ni], acc[mi][ni], 0, 0, 0);
    __builtin_amdgcn_s_setprio(0);
    // ---- tile end: counted vmcnt (never 0 in steady state) + barrier ----
    if (t < 29)       { asm volatile("s_waitcnt vmcnt(8)" ::: "memory"); }
    else if (t == 29) { asm volatile("s_waitcnt vmcnt(4)" ::: "memory"); }
    else if (t == 30) { asm volatile("s_waitcnt vmcnt(0)" ::: "memory"); }
    __builtin_amdgcn_s_barrier();
  }
  #undef STAGE_A
  #undef STAGE_B

  // ---- epilogue: bias + bf16 store, ni innermost (merge 128B lines) ------
  float bs[4];
  #pragma unroll
  for (int ni = 0; ni < 4; ++ni) bs[ni] = bias[bcol + wc * 64 + ni * 16 + r];
  bool isK = (bcol >= 1024 && bcol < 2048);   // block-uniform
  if (isK) {
    float ks[4] = {0.f, 0.f, 0.f, 0.f};
    #pragma unroll
    for (int mi = 0; mi < 8; ++mi)
      #pragma unroll
      for (int j = 0; j < 4; ++j) {
        int rowl = wr * 128 + mi * 16 + 4 * g + j;
        size_t rb = (size_t)(arow + rowl) * N3 + bcol + wc * 64 + r;
        #pragma unroll
        for (int ni = 0; ni < 4; ++ni) {
          unsigned short cv = f2b(acc[mi][ni][j] + bs[ni]);
          C[rb + ni * 16] = cv;
          ks[ni] += __expf(b2f(cv));   // exp of rounded value: matches attn
        }
      }
    int b = arow >> 10;
    #pragma unroll
    for (int ni = 0; ni < 4; ++ni) {
      float s = ks[ni];
      s += __shfl_xor(s, 16);
      s += __shfl_xor(s, 32);
      if (g == 0)
        atomicAdd(&ksum[b * 1024 + (bcol - 1024) + wc * 64 + ni * 16 + r], s);
    }
  } else {
    #pragma unroll
    for (int mi = 0; mi < 8; ++mi)
      #pragma unroll
      for (int j = 0; j < 4; ++j) {
        int rowl = wr * 128 + mi * 16 + 4 * g + j;
        size_t rb = (size_t)(arow + rowl) * N3 + bcol + wc * 64 + r;
        #pragma unroll
        for (int ni = 0; ni < 4; ++ni)
          C[rb + ni * 16] = f2b(acc[mi][ni][j] + bs[ni]);
      }
  }
}

// ---- K5: attn partials (bf16), 4-way split over T; k normalized on fly ----
__global__ __launch_bounds__(256) void attn_kernel(
    const unsigned short* __restrict__ qkv, const float* __restrict__ ksum,
    unsigned short* __restrict__ attnP)
{
  int bid = blockIdx.x;             // 2048
  int bh = bid >> 2, tq = bid & 3;
  int b = bh >> 4, h = bh & 15;
  int tid = threadIdx.x;
  int cgrp = tid & 7, trow = tid >> 3;   // staging: 8 col-groups x 32 t-rows
  int lane = tid & 63, wave = tid >> 6;
  int g = lane >> 4, r = lane & 15;
  __shared__ alignas(16) short lK[64 * 40];   // [col dd][t] transposed, pad 40
  __shared__ alignas(16) short lV[64 * 40];   // [col ll][t]
  const unsigned short* kb = qkv + ((size_t)(b * T_ + tq * 256)) * N3 + D_     + h * 64;
  const unsigned short* vb = qkv + ((size_t)(b * T_ + tq * 256)) * N3 + 2 * D_ + h * 64;
  float inv[8];
  const float* kp = ksum + b * 1024 + h * 64 + cgrp * 8;
  #pragma unroll
  for (int j = 0; j < 8; ++j) inv[j] = 1.f / kp[j];
  f32x4 acc[4] = {};
  short8 kv = *(const short8*)(kb + (size_t)trow * N3 + cgrp * 8);
  short8 vv = *(const short8*)(vb + (size_t)trow * N3 + cgrp * 8);
  for (int tc = 0; tc < 8; ++tc) {
    __syncthreads();
    #pragma unroll
    for (int j = 0; j < 8; ++j) {
      lK[(cgrp * 8 + j) * 40 + trow] =
          (short)f2b(__expf(b2f((unsigned short)kv[j])) * inv[j]);
      lV[(cgrp * 8 + j) * 40 + trow] = vv[j];
    }
    __syncthreads();
    if (tc < 7) {   // prefetch next chunk under ds_read + MFMA
      kv = *(const short8*)(kb + (size_t)((tc + 1) * 32 + trow) * N3 + cgrp * 8);
      vv = *(const short8*)(vb + (size_t)((tc + 1) * 32 + trow) * N3 + cgrp * 8);
    }
    short8 af = *(const short8*)(lK + (16 * wave + r) * 40 + 8 * g);
    #pragma unroll
    for (int ni = 0; ni < 4; ++ni) {
      short8 bf = *(const short8*)(lV + (16 * ni + r) * 40 + 8 * g);
      acc[ni] = __builtin_amdgcn_mfma_f32_16x16x32_bf16(af, bf, acc[ni], 0, 0, 0);
    }
  }
  unsigned short* op = attnP + (size_t)bid * 4096;
  #pragma unroll
  for (int ni = 0; ni < 4; ++ni)
    #pragma unroll
    for (int j = 0; j < 4; ++j) {
      int m = 16 * wave + 4 * g + j;   // dd
      int n = 16 * ni + r;             // ll
      op[(size_t)n * 64 + m] = f2b(acc[ni][j]);   // store transposed, bf16
    }
}

// ---- K5b: reduce 4 bf16 T-partials -> attnT bf16 --------------------------
__global__ __launch_bounds__(256) void attn_reduce(
    const unsigned short* __restrict__ attnP, unsigned short* __restrict__ attnT)
{
  int bh = blockIdx.x;             // 512
  int tid = threadIdx.x;
  const unsigned short* p0 = attnP + ((size_t)bh << 2) * 4096;
  unsigned short* o = attnT + (size_t)bh * 4096;
  #pragma unroll
  for (int it = 0; it < 2; ++it) {
    int i = (it * 256 + tid) * 8;
    short8 s0 = *(const short8*)(p0 + i);
    short8 s1 = *(const short8*)(p0 + 4096 + i);
    short8 s2 = *(const short8*)(p0 + 8192 + i);
    short8 s3 = *(const short8*)(p0 + 12288 + i);
    short8 ov;
    #pragma unroll
    for (int j = 0; j < 8; ++j) {
      float s = b2f((unsigned short)s0[j]) + b2f((unsigned short)s1[j])
              + b2f((unsigned short)s2[j]) + b2f((unsigned short)s3[j]);
      ov[j] = (short)f2b(s);
    }
    *(short8*)(o + i) = ov;
  }
}

// ---- K6: fused q-softmax + y = q_sm @ attn + residual ---------------------
// T14: residual x loads issued at kernel top; HBM latency hides under
// attnT staging + q-softmax + MFMA.
__global__ __launch_bounds__(256) void out_kernel(
    const unsigned short* __restrict__ qkv, const unsigned short* __restrict__ attnT,
    const float* __restrict__ x, float* __restrict__ out)
{
  int bid = blockIdx.x;             // 4096 = 512 bh * 8 row-tiles
  int bh = bid >> 3, mt = bid & 7;
  int b = bh >> 4, h = bh & 15;
  int tid = threadIdx.x;
  int lane = tid & 63, wave = tid >> 6;
  int g = lane >> 4, r = lane & 15;
  __shared__ alignas(16) short lAT[64 * 72];  // attn^T [ll][dd], pad 72
  __shared__ float lO[128][66];               // out tile f32, pad 66
  // ---- T14 prefetch: residual x, coalesced f32x4, issued first ----
  int rr = tid >> 4, c4 = (tid & 15) << 2;
  f32x4 xv[8];
  #pragma unroll
  for (int p = 0; p < 8; ++p) {
    int rowl = p * 16 + rr;
    size_t gi = ((size_t)(b * T_ + mt * 128 + rowl) << 10) + h * 64 + c4;
    xv[p] = *(const f32x4*)(x + gi);
  }
  const unsigned short* at = attnT + (size_t)bh * 4096;
  #pragma unroll
  for (int i = 0; i < 2; ++i) {
    int idx8 = (i * 256 + tid) * 8;
    int n = idx8 >> 6, kk0 = idx8 & 63;
    *(short8*)(lAT + n * 72 + kk0) = *(const short8*)(at + idx8);
  }
  __syncthreads();
  short8 bt[4][2];
  #pragma unroll
  for (int ni = 0; ni < 4; ++ni)
    #pragma unroll
    for (int kc = 0; kc < 2; ++kc)
      bt[ni][kc] = *(const short8*)(lAT + (16 * ni + r) * 72 + kc * 32 + 8 * g);
  int rowbase = mt * 128 + 32 * wave;
  const unsigned short* qb = qkv + (size_t)(b * T_ + rowbase) * N3 + h * 64;
  short8 aq[2][2];
  #pragma unroll
  for (int mi = 0; mi < 2; ++mi) {
    float qe[16];
    float s = 0.f;
    #pragma unroll
    for (int kc = 0; kc < 2; ++kc) {
      short8 qa = *(const short8*)(qb + (size_t)(16 * mi + r) * N3 + kc * 32 + 8 * g);
      #pragma unroll
      for (int j = 0; j < 8; ++j) {
        float e = __expf(b2f((unsigned short)qa[j]));
        qe[kc * 8 + j] = e;
        s += e;
      }
    }
    s += __shfl_xor(s, 16);
    s += __shfl_xor(s, 32);
    float inv = 1.f / s;
    #pragma unroll
    for (int kc = 0; kc < 2; ++kc) {
      short8 t8;
      #pragma unroll
      for (int j = 0; j < 8; ++j) t8[j] = (short)f2b(qe[kc * 8 + j] * inv);
      aq[mi][kc] = t8;
    }
  }
  f32x4 acc[2][4] = {};
  #pragma unroll
  for (int mi = 0; mi < 2; ++mi)
    #pragma unroll
    for (int kc = 0; kc < 2; ++kc)
      #pragma unroll
      for (int ni = 0; ni < 4; ++ni)
        acc[mi][ni] = __builtin_amdgcn_mfma_f32_16x16x32_bf16(aq[mi][kc], bt[ni][kc], acc[mi][ni], 0, 0, 0);
  // stage acc to LDS (2-way-max bank aliasing with pad 66)
  #pragma unroll
  for (int mi = 0; mi < 2; ++mi)
    #pragma unroll
    for (int ni = 0; ni < 4; ++ni)
      #pragma unroll
      for (int j = 0; j < 4; ++j)
        lO[32 * wave + 16 * mi + 4 * g + j][16 * ni + r] = acc[mi][ni][j];
  __syncthreads();
  // cooperative coalesced add+store: 16 threads/row, f32x4 each
  #pragma unroll
  for (int p = 0; p < 8; ++p) {
    int rowl = p * 16 + rr;
    size_t gi = ((size_t)(b * T_ + mt * 128 + rowl) << 10) + h * 64 + c4;
    f32x4 ov;
    ov[0] = xv[p][0] + lO[rowl][c4];
    ov[1] = xv[p][1] + lO[rowl][c4 + 1];
    ov[2] = xv[p][2] + lO[rowl][c4 + 2];
    ov[3] = xv[p][3] + lO[rowl][c4 + 3];
    *(f32x4*)(out + gi) = ov;
  }
}

extern "C" void kernel_launch(void* const* d_in, const int* in_sizes, int n_in,
                              void* d_out, int out_size, void* d_ws, size_t ws_size,
                              hipStream_t stream) {
  const float* x   = (const float*)d_in[0];
  const float* lng = (const float*)d_in[1];
  const float* lnb = (const float*)d_in[2];
  const float* Wq  = (const float*)d_in[3];
  const float* bq  = (const float*)d_in[4];
  const float* Wk  = (const float*)d_in[5];
  const float* bk  = (const float*)d_in[6];
  const float* Wv  = (const float*)d_in[7];
  const float* bv  = (const float*)d_in[8];
  float* out = (float*)d_out;
  char* ws = (char*)d_ws;
  // ws layout (bytes), 256-aligned:
  unsigned short* Wcat  = (unsigned short*)(ws + 0);          //   6,291,456
  float*          bias  = (float*)         (ws + 6291456);    //      12,288
  unsigned short* xn    = (unsigned short*)(ws + 6303744);    //  67,108,864
  unsigned short* qkv   = (unsigned short*)(ws + 73412608);   // 201,326,592
  unsigned short* attnT = (unsigned short*)(ws + 274739200);  //   4,194,304
  // attn bf16 partials reuse xn space (dead after gemm_qkv): 16.7 MB
  unsigned short* attnP = (unsigned short*)xn;
  // k-colsum scratch lives in d_out's first 128KB: zeroed by prep_kernel,
  // accumulated by gemm epilogue, read by attn, then fully overwritten by
  // out_kernel (which rewrites every element of d_out).
  float* ksum = (float*)d_out;
  prep_kernel<<<3072 + M_, 256, 0, stream>>>(Wq, Wk, Wv, bq, bk, bv,
                                             x, lng, lnb, Wcat, bias, ksum, xn);
  gemm_qkv   <<<1536,  512, 0, stream>>>(xn, Wcat, bias, qkv, ksum);
  attn_kernel<<<2048,  256, 0, stream>>>(qkv, ksum, attnP);
  attn_reduce<<<512,   256, 0, stream>>>(attnP, attnT);
  out_kernel <<<4096,  256, 0, stream>>>(qkv, attnT, x, out);
}